// Round 12
// baseline (283.423 us; speedup 1.0000x reference)
//
#include <hip/hip_runtime.h>

constexpr int N_NODES = 50000;
constexpr int N_EDGES = 800000;
constexpr int D = 128;
constexpr int CAP = 64;   // Poisson(16): P(deg>64) ~ 1e-24 (clamped anyway)

typedef float v2f __attribute__((ext_vector_type(2)));

// ---- Transpose table to slice-major: embT[s][n][16] = emb[n][s*16 .. s*16+15].
// Each 8-XCD slice becomes a dense 3.2MB region that FITS one XCD's 4MB L2.
__global__ void transpose_kernel(const float* __restrict__ emb,
                                 float* __restrict__ embT) {
    int tid = blockIdx.x * blockDim.x + threadIdx.x;    // 1.6M float4 tasks
    if (tid >= N_NODES * 32) return;
    int n  = tid >> 5;
    int r  = tid & 31;
    int s  = r >> 2;
    int kq = r & 3;
    float4 v = *(const float4*)(emb + (size_t)n * D + s * 16 + kq * 4);
    *(float4*)(embT + ((size_t)s * N_NODES + n) * 16 + kq * 4) = v;
}

// ---- Slot-array binning: u16 src (N_NODES < 65536) + per-node 64-bit flag mask.
__global__ void fill_kernel(const int* __restrict__ src,
                            const int* __restrict__ dst,
                            const int* __restrict__ ef,
                            int* __restrict__ counts,
                            unsigned short* __restrict__ slots,
                            unsigned int* __restrict__ flags) {
    int e = blockIdx.x * blockDim.x + threadIdx.x;
    if (e < N_EDGES) {
        int t = dst[e];
        int pos = atomicAdd(&counts[t], 1);
        if (pos < CAP) {
            slots[(size_t)t * CAP + pos] = (unsigned short)src[e];
            if (ef[e] == 0)
                atomicOr(&flags[t * 2 + (pos >> 5)], 1u << (pos & 31));
        }
    }
}

// ---- One wave = 8 nodes x 1 slice (8-lane groups, float2/lane = 64B/group/gather).
// blockIdx%8 selects the slice -> XCD round-robin keeps each slice's 3.2MB
// embT region resident in ONE XCD's L2. Slot u16s preloaded into 4 regs,
// broadcast via shfl (source lane always within the same 8-lane group).
template<bool TRANS>
__global__ void accumulate_kernel(const float* __restrict__ tab,
                                  const float* __restrict__ w,
                                  const int* __restrict__ counts,
                                  const unsigned int* __restrict__ slots2,
                                  const uint2* __restrict__ flags,
                                  float* __restrict__ out) {
    int slice = blockIdx.x & 7;
    int og    = blockIdx.x >> 3;
    int wid   = threadIdx.x >> 6;
    int lane  = threadIdx.x & 63;
    int g     = lane >> 3;
    int l8    = lane & 7;
    int octet = og * 4 + wid;
    if (octet >= N_NODES / 8) return;
    int n = octet * 8 + g;

    int c = counts[n]; if (c > CAP) c = CAP;
    uint2 fl = flags[n];
    const unsigned* sp = slots2 + (size_t)n * 32;   // 32 u32 = 64 u16 slots
    unsigned p0 = sp[l8], p1 = sp[l8 + 8], p2 = sp[l8 + 16], p3 = sp[l8 + 24];

    const float* base = TRANS ? tab + (size_t)slice * N_NODES * 16
                              : tab + slice * 16;
    float accx = 0.f, accy = 0.f, acc0x = 0.f, acc0y = 0.f;
    int gl = g << 3;

    auto chunk = [&](unsigned preg, int jbase, unsigned flw) {
        int je = c - jbase; if (je > 16) je = 16;
        for (int jj = 0; jj < je; ++jj) {
            unsigned pr = (unsigned)__shfl((int)preg, gl + (jj >> 1), 64);
            int s = (jj & 1) ? (int)(pr >> 16) : (int)(pr & 0xffffu);
            const float* ap = TRANS ? base + (size_t)s * 16 + (l8 << 1)
                                    : base + (size_t)s * D + (l8 << 1);
            v2f v = *(const v2f*)ap;
            accx += v.x; accy += v.y;
            if ((flw >> jj) & 1) { acc0x += v.x; acc0y += v.y; }
        }
    };
    chunk(p0,  0, fl.x);
    chunk(p1, 16, fl.x >> 16);
    chunk(p2, 32, fl.y);
    chunk(p3, 48, fl.y >> 16);

    v2f wv = *(const v2f*)(w + slice * 16 + (l8 << 1));
    v2f a, a0;
    a.x  = accx  * wv.x;  a.y  = accy  * wv.y;
    a0.x = acc0x * wv.x;  a0.y = acc0y * wv.y;
    const size_t ND = (size_t)N_NODES * D;
    float* o = out + (size_t)n * D + slice * 16 + (l8 << 1);
    __builtin_nontemporal_store(a,  (v2f*)o);
    __builtin_nontemporal_store(a0, (v2f*)(o + ND));
    __builtin_nontemporal_store(a0, (v2f*)(o + 2 * ND));
    __builtin_nontemporal_store(a0, (v2f*)(o + 3 * ND));
    __builtin_nontemporal_store(a0, (v2f*)(o + 4 * ND));
}

extern "C" void kernel_launch(void* const* d_in, const int* in_sizes, int n_in,
                              void* d_out, int out_size, void* d_ws, size_t ws_size,
                              hipStream_t stream) {
    const float* emb = (const float*)d_in[0];
    const float* w   = (const float*)d_in[1];
    const int*   src = (const int*)d_in[2];
    const int*   dst = (const int*)d_in[3];
    const int*   ef  = (const int*)d_in[4];
    float* out = (float*)d_out;

    // ws layout (byte offsets):
    //   counts: 0        .. 200192   (50048 int)
    //   flags : 200192   .. 600576   (50048 uint2)
    //   slots : 600576   .. 7000832  (50000*64 u16)
    //   embT  : 7000832  .. 32600832 (50000*128 f32)   [optional]
    char* wsb = (char*)d_ws;
    int*            counts = (int*)wsb;
    unsigned int*   flags  = (unsigned int*)(wsb + 200192);
    unsigned short* slots  = (unsigned short*)(wsb + 600576);
    float*          embT   = (float*)(wsb + 7000832);
    const bool trans = (ws_size >= 32600832);   // fallback if ws too small

    // zero counts + flags (0.6 MB)
    hipMemsetAsync(counts, 0, 600576, stream);

    if (trans)
        transpose_kernel<<<6250, 256, 0, stream>>>(emb, embT);

    fill_kernel<<<3125, 256, 0, stream>>>(src, dst, ef, counts, slots, flags);

    // 12504 blocks (divisible by 8 -> clean slice->XCD residue mapping)
    if (trans)
        accumulate_kernel<true><<<12504, 256, 0, stream>>>(embT, w, counts,
            (const unsigned int*)slots, (const uint2*)flags, out);
    else
        accumulate_kernel<false><<<12504, 256, 0, stream>>>(emb, w, counts,
            (const unsigned int*)slots, (const uint2*)flags, out);
}

// Round 14
// 279.438 us; speedup vs baseline: 1.0143x; 1.0143x over previous
//
#include <hip/hip_runtime.h>

constexpr int N_NODES = 50000;
constexpr int N_EDGES = 800000;
constexpr int D = 128;
constexpr int CAP = 64;   // Poisson(16): P(deg>64) ~ 1e-24 (clamped anyway)

typedef float v2f __attribute__((ext_vector_type(2)));

// ---- Transpose table to slice-major: embT[s][n][16] = emb[n][s*16 .. s*16+15].
// Each 8-XCD slice is a dense 3.2MB region that fits one XCD's 4MB L2
// (VERIFIED R12: FETCH 179 -> 53 MB).
__global__ void transpose_kernel(const float* __restrict__ emb,
                                 float* __restrict__ embT) {
    int tid = blockIdx.x * blockDim.x + threadIdx.x;    // 1.6M float4 tasks
    if (tid >= N_NODES * 32) return;
    int n  = tid >> 5;
    int r  = tid & 31;
    int s  = r >> 2;
    int kq = r & 3;
    float4 v = *(const float4*)(emb + (size_t)n * D + s * 16 + kq * 4);
    *(float4*)(embT + ((size_t)s * N_NODES + n) * 16 + kq * 4) = v;
}

// ---- Slot-array binning: u16 src (N_NODES < 65536) + per-node 64-bit flag mask.
__global__ void fill_kernel(const int* __restrict__ src,
                            const int* __restrict__ dst,
                            const int* __restrict__ ef,
                            int* __restrict__ counts,
                            unsigned short* __restrict__ slots,
                            unsigned int* __restrict__ flags) {
    int e = blockIdx.x * blockDim.x + threadIdx.x;
    if (e < N_EDGES) {
        int t = dst[e];
        int pos = atomicAdd(&counts[t], 1);
        if (pos < CAP) {
            slots[(size_t)t * CAP + pos] = (unsigned short)src[e];
            if (ef[e] == 0)
                atomicOr(&flags[t * 2 + (pos >> 5)], 1u << (pos & 31));
        }
    }
}

// ---- One wave = 8 nodes x 1 slice. R13 restructure: latency-bound -> MLP.
//  * indices re-read from L2-resident slots as group-uniform uint2 (4 idx/load)
//    -- replaces the serial ds_bpermute chain (R12: ~288 cyc/edge exposed)
//  * 4 independent gathers in flight per batch
//  * predicated accumulate to wave-max degree (no exec-mask divergence;
//    dead lanes gather row 0 = hot line)
template<bool TRANS>
__global__ void accumulate_kernel(const float* __restrict__ tab,
                                  const float* __restrict__ w,
                                  const int* __restrict__ counts,
                                  const unsigned short* __restrict__ slots,
                                  const uint2* __restrict__ flags,
                                  float* __restrict__ out) {
    constexpr int STRIDE = TRANS ? 16 : D;
    int slice = blockIdx.x & 7;
    int og    = blockIdx.x >> 3;
    int wid   = threadIdx.x >> 6;
    int lane  = threadIdx.x & 63;
    int g     = lane >> 3;
    int l8    = lane & 7;
    int octet = og * 4 + wid;
    if (octet >= N_NODES / 8) return;
    int n = octet * 8 + g;

    int c = counts[n]; if (c > CAP) c = CAP;
    uint2 fl = flags[n];
    unsigned long long F = ((unsigned long long)fl.y << 32) | (unsigned long long)fl.x;

    // wave-wide max degree over the 8 groups (c is uniform within a group)
    int m = c;
    m = max(m, __shfl_xor(m, 8, 64));
    m = max(m, __shfl_xor(m, 16, 64));
    m = max(m, __shfl_xor(m, 32, 64));

    const float* bp = (TRANS ? tab + (size_t)slice * N_NODES * 16
                             : tab + slice * 16) + (l8 << 1);
    const unsigned short* sl = slots + (size_t)n * CAP;

    float accx = 0.f, accy = 0.f, acc0x = 0.f, acc0y = 0.f;

    for (int j = 0; j < m; j += 4) {
        // 4 indices in one group-uniform 8B load (L2-resident, cache broadcast)
        uint2 iw = *(const uint2*)(sl + j);
        bool p0 = (j     < c), p1 = (j + 1 < c), p2 = (j + 2 < c), p3 = (j + 3 < c);
        int s0 = p0 ? (int)(iw.x & 0xffffu) : 0;
        int s1 = p1 ? (int)(iw.x >> 16)     : 0;
        int s2 = p2 ? (int)(iw.y & 0xffffu) : 0;
        int s3 = p3 ? (int)(iw.y >> 16)     : 0;
        // 4 independent gathers -> all in flight before first use
        v2f v0 = *(const v2f*)(bp + (size_t)s0 * STRIDE);
        v2f v1 = *(const v2f*)(bp + (size_t)s1 * STRIDE);
        v2f v2 = *(const v2f*)(bp + (size_t)s2 * STRIDE);
        v2f v3 = *(const v2f*)(bp + (size_t)s3 * STRIDE);
        unsigned Fs = (unsigned)(F >> j);
        bool q0 = p0 && (Fs & 1u), q1 = p1 && (Fs & 2u),
             q2 = p2 && (Fs & 4u), q3 = p3 && (Fs & 8u);
        accx  += (p0 ? v0.x : 0.f) + (p1 ? v1.x : 0.f)
               + (p2 ? v2.x : 0.f) + (p3 ? v3.x : 0.f);
        accy  += (p0 ? v0.y : 0.f) + (p1 ? v1.y : 0.f)
               + (p2 ? v2.y : 0.f) + (p3 ? v3.y : 0.f);
        acc0x += (q0 ? v0.x : 0.f) + (q1 ? v1.x : 0.f)
               + (q2 ? v2.x : 0.f) + (q3 ? v3.x : 0.f);
        acc0y += (q0 ? v0.y : 0.f) + (q1 ? v1.y : 0.f)
               + (q2 ? v2.y : 0.f) + (q3 ? v3.y : 0.f);
    }

    v2f wv = *(const v2f*)(w + slice * 16 + (l8 << 1));
    v2f a, a0;
    a.x  = accx  * wv.x;  a.y  = accy  * wv.y;
    a0.x = acc0x * wv.x;  a0.y = acc0y * wv.y;
    const size_t ND = (size_t)N_NODES * D;
    float* o = out + (size_t)n * D + slice * 16 + (l8 << 1);
    __builtin_nontemporal_store(a,  (v2f*)o);
    __builtin_nontemporal_store(a0, (v2f*)(o + ND));
    __builtin_nontemporal_store(a0, (v2f*)(o + 2 * ND));
    __builtin_nontemporal_store(a0, (v2f*)(o + 3 * ND));
    __builtin_nontemporal_store(a0, (v2f*)(o + 4 * ND));
}

extern "C" void kernel_launch(void* const* d_in, const int* in_sizes, int n_in,
                              void* d_out, int out_size, void* d_ws, size_t ws_size,
                              hipStream_t stream) {
    const float* emb = (const float*)d_in[0];
    const float* w   = (const float*)d_in[1];
    const int*   src = (const int*)d_in[2];
    const int*   dst = (const int*)d_in[3];
    const int*   ef  = (const int*)d_in[4];
    float* out = (float*)d_out;

    // ws layout (byte offsets):
    //   counts: 0        .. 200192   (50048 int)
    //   flags : 200192   .. 600576   (50048 uint2)
    //   slots : 600576   .. 7000832  (50000*64 u16)
    //   embT  : 7000832  .. 32600832 (50000*128 f32)   [optional]
    char* wsb = (char*)d_ws;
    int*            counts = (int*)wsb;
    unsigned int*   flags  = (unsigned int*)(wsb + 200192);
    unsigned short* slots  = (unsigned short*)(wsb + 600576);
    float*          embT   = (float*)(wsb + 7000832);
    const bool trans = (ws_size >= 32600832);   // fallback if ws too small

    // zero counts + flags (0.6 MB)
    hipMemsetAsync(counts, 0, 600576, stream);

    if (trans)
        transpose_kernel<<<6250, 256, 0, stream>>>(emb, embT);

    fill_kernel<<<3125, 256, 0, stream>>>(src, dst, ef, counts, slots, flags);

    // 12504 blocks (divisible by 8 -> clean slice->XCD residue mapping)
    if (trans)
        accumulate_kernel<true><<<12504, 256, 0, stream>>>(embT, w, counts,
            slots, (const uint2*)flags, out);
    else
        accumulate_kernel<false><<<12504, 256, 0, stream>>>(emb, w, counts,
            slots, (const uint2*)flags, out);
}